// Round 1
// baseline (571.982 us; speedup 1.0000x reference)
//
#include <hip/hip_runtime.h>

#define HO 62
#define WO 62
#define CIN 32
#define COUT 64
#define BATCH 16
#define KROW 288           // CIN*3*3, contiguous k per (position,o)
#define JT 4               // j positions per block
#define COLS 6             // JT + 2 window columns

// 4-byte-aligned float4 for weight loads (k offset c*9 is not 16B aligned)
typedef float f4a4 __attribute__((ext_vector_type(4), aligned(4)));

__global__ __launch_bounds__(256, 4)
void lc2d_kernel(const float* __restrict__ x,
                 const float* __restrict__ wgt,
                 float* __restrict__ out) {
    // x window for 4 adjacent output columns: [c][kh][col][batch]
    __shared__ __align__(16) float win[CIN][3][COLS][BATCH];

    const int blk = blockIdx.x;
    const int i  = blk % HO;          // consecutive blocks share x rows (L2 locality)
    const int j0 = (blk / HO) * JT;

    const int t = threadIdx.x;

    // ---- stage x window: 16b * 32c * 3kh rows of 6 cols = 9216 floats ----
    // b fastest across lanes -> 16 distinct banks, ~4-way conflict on writes (cheap, one-time)
    for (int r = t; r < BATCH * CIN * 3; r += 256) {
        const int b   = r & 15;
        const int ckh = r >> 4;            // 0..95
        const int c   = ckh / 3;
        const int kh  = ckh % 3;
        const float* src = x + (((b * CIN + c) * 64) + (i + kh)) * 64;
        #pragma unroll
        for (int cc = 0; cc < COLS; cc++) {
            int col = j0 + cc;
            if (col > 63) col = 63;        // clamp for last tile; garbage only feeds dead j
            win[c][kh][cc][b] = src[col];
        }
    }
    __syncthreads();

    const int wsel = t >> 6;   // wave id = batch-quad (b = wsel*4 + bb)
    const int o    = t & 63;   // lane = output channel

    // weight row pointers for this thread's 4 j positions
    const float* wj[JT];
    #pragma unroll
    for (int jj = 0; jj < JT; jj++) {
        int pj = i * WO + (j0 + jj);
        if (pj > HO * WO - 1) pj = HO * WO - 1;   // clamp dead j (result discarded)
        wj[jj] = wgt + (size_t)pj * (COUT * KROW) + o * KROW;
    }

    float acc[JT][4];   // [jj][bb]
    #pragma unroll
    for (int jj = 0; jj < JT; jj++)
        #pragma unroll
        for (int bb = 0; bb < 4; bb++) acc[jj][bb] = 0.0f;

    const float* xbase = &win[0][0][0][wsel * 4];  // wave-uniform -> LDS broadcast reads

    for (int c = 0; c < CIN; c++) {
        // 9 weights per j-position: two unaligned float4 + one scalar
        float wq[JT][9];
        #pragma unroll
        for (int jj = 0; jj < JT; jj++) {
            const float* p = wj[jj] + c * 9;
            const f4a4 wA = *(const f4a4*)p;
            const f4a4 wB = *(const f4a4*)(p + 4);
            wq[jj][0] = wA.x; wq[jj][1] = wA.y; wq[jj][2] = wA.z; wq[jj][3] = wA.w;
            wq[jj][4] = wB.x; wq[jj][5] = wB.y; wq[jj][6] = wB.z; wq[jj][7] = wB.w;
            wq[jj][8] = p[8];
        }
        #pragma unroll
        for (int kh = 0; kh < 3; kh++) {
            // 6 window columns, each a 16B broadcast read (same address all 64 lanes)
            float4 xv[COLS];
            const float* xb = xbase + (c * 3 + kh) * (COLS * BATCH);
            #pragma unroll
            for (int cc = 0; cc < COLS; cc++)
                xv[cc] = *(const float4*)(xb + cc * BATCH);
            #pragma unroll
            for (int jj = 0; jj < JT; jj++) {
                #pragma unroll
                for (int kw = 0; kw < 3; kw++) {
                    const float w = wq[jj][kh * 3 + kw];
                    const float4 xx = xv[jj + kw];
                    acc[jj][0] += w * xx.x;
                    acc[jj][1] += w * xx.y;
                    acc[jj][2] += w * xx.z;
                    acc[jj][3] += w * xx.w;
                }
            }
        }
    }

    // ---- epilogue: sigmoid + float2 stores along j (8B aligned: j0 % 4 == 0) ----
    #pragma unroll
    for (int bb = 0; bb < 4; bb++) {
        const int b = wsel * 4 + bb;
        float* op = out + (((size_t)(b * COUT + o) * HO + i) * WO + j0);
        float2 s0;
        s0.x = 1.0f / (1.0f + __expf(-acc[0][bb]));
        s0.y = 1.0f / (1.0f + __expf(-acc[1][bb]));
        *(float2*)op = s0;
        if (j0 + 3 < WO) {               // last tile (j0=60) has only 2 valid columns
            float2 s1;
            s1.x = 1.0f / (1.0f + __expf(-acc[2][bb]));
            s1.y = 1.0f / (1.0f + __expf(-acc[3][bb]));
            *((float2*)op + 1) = s1;
        }
    }
}

extern "C" void kernel_launch(void* const* d_in, const int* in_sizes, int n_in,
                              void* d_out, int out_size, void* d_ws, size_t ws_size,
                              hipStream_t stream) {
    const float* x   = (const float*)d_in[0];
    const float* wgt = (const float*)d_in[1];
    float* out       = (float*)d_out;
    const int grid = HO * ((WO + JT - 1) / JT);   // 62 * 16 = 992 blocks
    lc2d_kernel<<<dim3(grid), dim3(256), 0, stream>>>(x, wgt, out);
}